// Round 8
// baseline (118.396 us; speedup 1.0000x reference)
//
#include <hip/hip_runtime.h>

// PointPillarScatter: out[b][c][y][x] = pf[b][p][c] where coords[b][p] = (b,0,y,x), else 0.
// B=8, P=20000, C=64, NX=432, NY=496. Output (8,64,496,432) fp32.
//
// Gather formulation (R5 structure — best so far):
//   K1: map16[b][cell] = 0xFFFF                 (ushort map: 3.4 MB)
//   K2: map16[b][y*NX+x] = p                    (p < 20000 < 0xFFFF)
//   K3: one thread per (b, 4-cell group); loops all 16 channel-quads.
//       Conditional exec-masked loads: only 9.3% of cells are occupied, so
//       ~91% of load lanes are masked off (cheap). 64-thread blocks,
//       chunked XCD swizzle (6696 = 8 x 837, one batch per XCD).
//   R8 single-variable change vs R5: PLAIN stores instead of nontemporal.
//       L2 write-back acts as a reorder buffer -> DRAM sees sequential
//       streams (the 7 TB/s fill kernels use plain stores).

#define BB    8
#define PP    20000
#define CC    64
#define NXX   432
#define NYY   496
#define NCELL (NXX * NYY)   /* 214272 */
#define NCELL4 (NCELL / 4)  /* 53568  */

#define GBLK   64
#define GNWG   ((BB * NCELL4) / GBLK)  /* 428544/64 = 6696 exactly */
#define NXCD   8
#define CHUNK  (GNWG / NXCD)           /* 837: exactly one batch per XCD */

typedef float f32x4 __attribute__((ext_vector_type(4)));
typedef unsigned short u16;
typedef u16 u16x4 __attribute__((ext_vector_type(4)));

__global__ void ppsc_init_map(int* __restrict__ map16_as_int, int n4) {
    int t = blockIdx.x * blockDim.x + threadIdx.x;
    if (t < n4) ((int4*)map16_as_int)[t] = make_int4(-1, -1, -1, -1);  // all 0xFFFF
}

__global__ void ppsc_scatter_map(const int* __restrict__ coords, u16* __restrict__ map16) {
    int t = blockIdx.x * blockDim.x + threadIdx.x;  // one thread per (b,p)
    if (t >= BB * PP) return;
    int b = t / PP;
    int p = t - b * PP;
    const int4 c4 = ((const int4*)coords)[t];       // [b, z, y, x] as int32
    int y = c4.z, x = c4.w;
    if ((unsigned)y < (unsigned)NYY && (unsigned)x < (unsigned)NXX)
        map16[(size_t)b * NCELL + y * NXX + x] = (u16)p;
}

// one thread per (b, cell-quad); all 64 channels.
__global__ void __launch_bounds__(GBLK) ppsc_gather_all(const float* __restrict__ pf,
                                                        const u16* __restrict__ map16,
                                                        float* __restrict__ out) {
    // chunked XCD swizzle: hardware bids round-robin XCDs; remap so XCD k owns
    // contiguous blocks [k*CHUNK,(k+1)*CHUNK) == exactly batch k.
    int bid = blockIdx.x;
    int wg  = (bid % NXCD) * CHUNK + bid / NXCD;

    int t  = wg * GBLK + threadIdx.x;
    int i4 = t % NCELL4;
    int b  = t / NCELL4;

    u16x4 m = ((const u16x4*)(map16 + (size_t)b * NCELL))[i4];
    const float* base = pf + (size_t)b * PP * CC;
    const float* p0 = base + (size_t)m.x * CC;
    const float* p1 = base + (size_t)m.y * CC;
    const float* p2 = base + (size_t)m.z * CC;
    const float* p3 = base + (size_t)m.w * CC;
    bool v0 = (m.x != 0xFFFFu), v1 = (m.y != 0xFFFFu),
         v2 = (m.z != 0xFFFFu), v3 = (m.w != 0xFFFFu);

    float* ob = out + (size_t)b * CC * NCELL + (size_t)i4 * 4;

#pragma unroll
    for (int cq = 0; cq < 16; ++cq) {
        f32x4 o0 = (f32x4)0.f, o1 = (f32x4)0.f, o2 = (f32x4)0.f, o3 = (f32x4)0.f;
        if (v0) { f32x4 f = *(const f32x4*)(p0 + cq * 4);
                  o0.x = f.x; o1.x = f.y; o2.x = f.z; o3.x = f.w; }
        if (v1) { f32x4 f = *(const f32x4*)(p1 + cq * 4);
                  o0.y = f.x; o1.y = f.y; o2.y = f.z; o3.y = f.w; }
        if (v2) { f32x4 f = *(const f32x4*)(p2 + cq * 4);
                  o0.z = f.x; o1.z = f.y; o2.z = f.z; o3.z = f.w; }
        if (v3) { f32x4 f = *(const f32x4*)(p3 + cq * 4);
                  o0.w = f.x; o1.w = f.y; o2.w = f.z; o3.w = f.w; }
        float* op = ob + (size_t)(cq * 4) * NCELL;
        *((f32x4*)op)                        = o0;
        *((f32x4*)(op + (size_t)NCELL))      = o1;
        *((f32x4*)(op + 2 * (size_t)NCELL))  = o2;
        *((f32x4*)(op + 3 * (size_t)NCELL))  = o3;
    }
}

// ---- fallback path (ws too small): zero output + direct scatter ----
__global__ void ppsc_zero(float* __restrict__ out, int n4) {
    int t = blockIdx.x * blockDim.x + threadIdx.x;
    if (t < n4) ((float4*)out)[t] = make_float4(0.f, 0.f, 0.f, 0.f);
}

__global__ void ppsc_direct_scatter(const float* __restrict__ pf,
                                    const int* __restrict__ coords,
                                    float* __restrict__ out) {
    int t = blockIdx.x * blockDim.x + threadIdx.x;  // one thread per (b,p,c)
    if (t >= BB * PP * CC) return;
    int c  = t % CC;
    int bp = t / CC;
    int b  = bp / PP;
    const int* cd = coords + (size_t)bp * 4;
    int y = cd[2], x = cd[3];
    if ((unsigned)y < (unsigned)NYY && (unsigned)x < (unsigned)NXX)
        out[((size_t)(b * CC + c)) * NCELL + (size_t)y * NXX + x] = pf[(size_t)bp * CC + c];
}

extern "C" void kernel_launch(void* const* d_in, const int* in_sizes, int n_in,
                              void* d_out, int out_size, void* d_ws, size_t ws_size,
                              hipStream_t stream) {
    const float* pf     = (const float*)d_in[0];
    const int*   coords = (const int*)d_in[1];
    float*       out    = (float*)d_out;

    const size_t map_bytes = (size_t)BB * NCELL * sizeof(u16);  // 3.43 MB

    if (ws_size >= map_bytes) {
        u16* map16 = (u16*)d_ws;

        int n4_map = (int)(map_bytes / 16);  // 214272 int4 writes
        ppsc_init_map<<<(n4_map + 255) / 256, 256, 0, stream>>>((int*)map16, n4_map);

        int npil = BB * PP;                  // 160000
        ppsc_scatter_map<<<(npil + 255) / 256, 256, 0, stream>>>(coords, map16);

        ppsc_gather_all<<<GNWG, GBLK, 0, stream>>>(pf, map16, out);
    } else {
        int n4_out = out_size / 4;
        ppsc_zero<<<(n4_out + 255) / 256, 256, 0, stream>>>(out, n4_out);

        int nsc = BB * PP * CC;              // 10,240,000
        ppsc_direct_scatter<<<(nsc + 255) / 256, 256, 0, stream>>>(pf, coords, out);
    }
}

// Round 9
// 95.191 us; speedup vs baseline: 1.2438x; 1.2438x over previous
//
#include <hip/hip_runtime.h>

// PointPillarScatter: out[b][c][y][x] = pf[b][p][c] where coords[b][p] = (b,0,y,x), else 0.
// B=8, P=20000, C=64, NX=432, NY=496. Output (8,64,496,432) fp32.
//
// Gather formulation (R5 structure, init-free):
//   K1 (scatter): map16[b][y*NX+x] = p    — NO clearing pass needed.
//   K2 (gather): one thread per (b, 4-cell group); loops 16 channel-quads.
//       Map entries are validated by a REVERSE CHECK: entry q is used only if
//       q < P and coords[b][q] maps back to this cell. Any junk in ws (0xAA
//       poison, stale data, zeros) either fails the check or is coincidentally
//       correct (coords unique per batch => if coords[b][q]->i, q IS i's
//       pillar). Correct for arbitrary ws contents on every call.
//       NT stores (R8 A/B: plain stores +21us). u16 map. 64-thr blocks.
//       Chunked XCD swizzle: 6696 = 8 x 837, one batch per XCD.

#define BB    8
#define PP    20000
#define CC    64
#define NXX   432
#define NYY   496
#define NCELL (NXX * NYY)   /* 214272 */
#define NCELL4 (NCELL / 4)  /* 53568  */

#define GBLK   64
#define GNWG   ((BB * NCELL4) / GBLK)  /* 428544/64 = 6696 exactly */
#define NXCD   8
#define CHUNK  (GNWG / NXCD)           /* 837: exactly one batch per XCD */

typedef float f32x4 __attribute__((ext_vector_type(4)));
typedef unsigned short u16;
typedef u16 u16x4 __attribute__((ext_vector_type(4)));

__global__ void ppsc_scatter_map(const int* __restrict__ coords, u16* __restrict__ map16) {
    int t = blockIdx.x * blockDim.x + threadIdx.x;  // one thread per (b,p)
    if (t >= BB * PP) return;
    int b = t / PP;
    int p = t - b * PP;
    const int4 c4 = ((const int4*)coords)[t];       // [b, z, y, x] as int32
    int y = c4.z, x = c4.w;
    if ((unsigned)y < (unsigned)NYY && (unsigned)x < (unsigned)NXX)
        map16[(size_t)b * NCELL + y * NXX + x] = (u16)p;
}

// one thread per (b, cell-quad); all 64 channels.
__global__ void __launch_bounds__(GBLK) ppsc_gather_all(const float* __restrict__ pf,
                                                        const u16* __restrict__ map16,
                                                        const int* __restrict__ coords,
                                                        float* __restrict__ out) {
    // chunked XCD swizzle: hardware bids round-robin XCDs; remap so XCD k owns
    // contiguous blocks [k*CHUNK,(k+1)*CHUNK) == exactly batch k.
    int bid = blockIdx.x;
    int wg  = (bid % NXCD) * CHUNK + bid / NXCD;

    int t  = wg * GBLK + threadIdx.x;
    int i4 = t % NCELL4;
    int b  = t / NCELL4;

    u16x4 m = ((const u16x4*)(map16 + (size_t)b * NCELL))[i4];
    const int4* cb = ((const int4*)coords) + (size_t)b * PP;
    int cell0 = i4 * 4;

    // reverse-validate each map entry: junk-proof, init-free.
    bool v0 = (m.x < PP), v1 = (m.y < PP), v2 = (m.z < PP), v3 = (m.w < PP);
    if (v0) { int4 c = cb[m.x]; v0 = (c.z * NXX + c.w) == cell0;     }
    if (v1) { int4 c = cb[m.y]; v1 = (c.z * NXX + c.w) == cell0 + 1; }
    if (v2) { int4 c = cb[m.z]; v2 = (c.z * NXX + c.w) == cell0 + 2; }
    if (v3) { int4 c = cb[m.w]; v3 = (c.z * NXX + c.w) == cell0 + 3; }

    const float* base = pf + (size_t)b * PP * CC;
    const float* p0 = base + (size_t)m.x * CC;
    const float* p1 = base + (size_t)m.y * CC;
    const float* p2 = base + (size_t)m.z * CC;
    const float* p3 = base + (size_t)m.w * CC;

    float* ob = out + (size_t)b * CC * NCELL + (size_t)cell0;

#pragma unroll
    for (int cq = 0; cq < 16; ++cq) {
        f32x4 o0 = (f32x4)0.f, o1 = (f32x4)0.f, o2 = (f32x4)0.f, o3 = (f32x4)0.f;
        if (v0) { f32x4 f = *(const f32x4*)(p0 + cq * 4);
                  o0.x = f.x; o1.x = f.y; o2.x = f.z; o3.x = f.w; }
        if (v1) { f32x4 f = *(const f32x4*)(p1 + cq * 4);
                  o0.y = f.x; o1.y = f.y; o2.y = f.z; o3.y = f.w; }
        if (v2) { f32x4 f = *(const f32x4*)(p2 + cq * 4);
                  o0.z = f.x; o1.z = f.y; o2.z = f.z; o3.z = f.w; }
        if (v3) { f32x4 f = *(const f32x4*)(p3 + cq * 4);
                  o0.w = f.x; o1.w = f.y; o2.w = f.z; o3.w = f.w; }
        float* op = ob + (size_t)(cq * 4) * NCELL;
        __builtin_nontemporal_store(o0, (f32x4*)op);
        __builtin_nontemporal_store(o1, (f32x4*)(op + (size_t)NCELL));
        __builtin_nontemporal_store(o2, (f32x4*)(op + 2 * (size_t)NCELL));
        __builtin_nontemporal_store(o3, (f32x4*)(op + 3 * (size_t)NCELL));
    }
}

// ---- fallback path (ws too small): zero output + direct scatter ----
__global__ void ppsc_zero(float* __restrict__ out, int n4) {
    int t = blockIdx.x * blockDim.x + threadIdx.x;
    if (t < n4) ((float4*)out)[t] = make_float4(0.f, 0.f, 0.f, 0.f);
}

__global__ void ppsc_direct_scatter(const float* __restrict__ pf,
                                    const int* __restrict__ coords,
                                    float* __restrict__ out) {
    int t = blockIdx.x * blockDim.x + threadIdx.x;  // one thread per (b,p,c)
    if (t >= BB * PP * CC) return;
    int c  = t % CC;
    int bp = t / CC;
    int b  = bp / PP;
    const int* cd = coords + (size_t)bp * 4;
    int y = cd[2], x = cd[3];
    if ((unsigned)y < (unsigned)NYY && (unsigned)x < (unsigned)NXX)
        out[((size_t)(b * CC + c)) * NCELL + (size_t)y * NXX + x] = pf[(size_t)bp * CC + c];
}

extern "C" void kernel_launch(void* const* d_in, const int* in_sizes, int n_in,
                              void* d_out, int out_size, void* d_ws, size_t ws_size,
                              hipStream_t stream) {
    const float* pf     = (const float*)d_in[0];
    const int*   coords = (const int*)d_in[1];
    float*       out    = (float*)d_out;

    const size_t map_bytes = (size_t)BB * NCELL * sizeof(u16);  // 3.43 MB

    if (ws_size >= map_bytes) {
        u16* map16 = (u16*)d_ws;

        int npil = BB * PP;                  // 160000
        ppsc_scatter_map<<<(npil + 255) / 256, 256, 0, stream>>>(coords, map16);

        ppsc_gather_all<<<GNWG, GBLK, 0, stream>>>(pf, map16, coords, out);
    } else {
        int n4_out = out_size / 4;
        ppsc_zero<<<(n4_out + 255) / 256, 256, 0, stream>>>(out, n4_out);

        int nsc = BB * PP * CC;              // 10,240,000
        ppsc_direct_scatter<<<(nsc + 255) / 256, 256, 0, stream>>>(pf, coords, out);
    }
}

// Round 10
// 94.748 us; speedup vs baseline: 1.2496x; 1.0047x over previous
//
#include <hip/hip_runtime.h>

// PointPillarScatter: out[b][c][y][x] = pf[b][p][c] where coords[b][p] = (b,0,y,x), else 0.
// B=8, P=20000, C=64, NX=432, NY=496. Output (8,64,496,432) fp32.
//
// Gather formulation (R9 structure, init-free):
//   K1 (scatter): map16[b][y*NX+x] = p    — no clearing pass.
//   K2 (gather): one thread per (b, 4-cell group); loops 16 channel-quads.
//       Reverse-check validation: entry q used only if q < P and coords[b][q]
//       maps back to this cell -> correct for arbitrary ws junk (poison/stale).
//       NT stores (R8 A/B: plain +21us). u16 map. 64-thr blocks.
//       Chunked XCD swizzle: 6696 = 8 x 837, one batch per XCD.
//   R10 single-variable change vs R9: __launch_bounds__(64,8) + unroll 4
//       to cap VGPR <= 64 so all ~26 blocks/CU are co-resident (one dispatch
//       round, full latency hiding) instead of ~20-24 + a serialized tail.

#define BB    8
#define PP    20000
#define CC    64
#define NXX   432
#define NYY   496
#define NCELL (NXX * NYY)   /* 214272 */
#define NCELL4 (NCELL / 4)  /* 53568  */

#define GBLK   64
#define GNWG   ((BB * NCELL4) / GBLK)  /* 428544/64 = 6696 exactly */
#define NXCD   8
#define CHUNK  (GNWG / NXCD)           /* 837: exactly one batch per XCD */

typedef float f32x4 __attribute__((ext_vector_type(4)));
typedef unsigned short u16;
typedef u16 u16x4 __attribute__((ext_vector_type(4)));

__global__ void ppsc_scatter_map(const int* __restrict__ coords, u16* __restrict__ map16) {
    int t = blockIdx.x * blockDim.x + threadIdx.x;  // one thread per (b,p)
    if (t >= BB * PP) return;
    int b = t / PP;
    int p = t - b * PP;
    const int4 c4 = ((const int4*)coords)[t];       // [b, z, y, x] as int32
    int y = c4.z, x = c4.w;
    if ((unsigned)y < (unsigned)NYY && (unsigned)x < (unsigned)NXX)
        map16[(size_t)b * NCELL + y * NXX + x] = (u16)p;
}

// one thread per (b, cell-quad); all 64 channels.
__global__ void __launch_bounds__(GBLK, 8) ppsc_gather_all(const float* __restrict__ pf,
                                                           const u16* __restrict__ map16,
                                                           const int* __restrict__ coords,
                                                           float* __restrict__ out) {
    // chunked XCD swizzle: hardware bids round-robin XCDs; remap so XCD k owns
    // contiguous blocks [k*CHUNK,(k+1)*CHUNK) == exactly batch k.
    int bid = blockIdx.x;
    int wg  = (bid % NXCD) * CHUNK + bid / NXCD;

    int t  = wg * GBLK + threadIdx.x;
    int i4 = t % NCELL4;
    int b  = t / NCELL4;

    u16x4 m = ((const u16x4*)(map16 + (size_t)b * NCELL))[i4];
    const int4* cb = ((const int4*)coords) + (size_t)b * PP;
    int cell0 = i4 * 4;

    // reverse-validate each map entry: junk-proof, init-free.
    bool v0 = (m.x < PP), v1 = (m.y < PP), v2 = (m.z < PP), v3 = (m.w < PP);
    if (v0) { int4 c = cb[m.x]; v0 = (c.z * NXX + c.w) == cell0;     }
    if (v1) { int4 c = cb[m.y]; v1 = (c.z * NXX + c.w) == cell0 + 1; }
    if (v2) { int4 c = cb[m.z]; v2 = (c.z * NXX + c.w) == cell0 + 2; }
    if (v3) { int4 c = cb[m.w]; v3 = (c.z * NXX + c.w) == cell0 + 3; }

    const float* base = pf + (size_t)b * PP * CC;
    const float* p0 = base + (size_t)m.x * CC;
    const float* p1 = base + (size_t)m.y * CC;
    const float* p2 = base + (size_t)m.z * CC;
    const float* p3 = base + (size_t)m.w * CC;

    float* ob = out + (size_t)b * CC * NCELL + (size_t)cell0;

#pragma unroll 4
    for (int cq = 0; cq < 16; ++cq) {
        f32x4 o0 = (f32x4)0.f, o1 = (f32x4)0.f, o2 = (f32x4)0.f, o3 = (f32x4)0.f;
        if (v0) { f32x4 f = *(const f32x4*)(p0 + cq * 4);
                  o0.x = f.x; o1.x = f.y; o2.x = f.z; o3.x = f.w; }
        if (v1) { f32x4 f = *(const f32x4*)(p1 + cq * 4);
                  o0.y = f.x; o1.y = f.y; o2.y = f.z; o3.y = f.w; }
        if (v2) { f32x4 f = *(const f32x4*)(p2 + cq * 4);
                  o0.z = f.x; o1.z = f.y; o2.z = f.z; o3.z = f.w; }
        if (v3) { f32x4 f = *(const f32x4*)(p3 + cq * 4);
                  o0.w = f.x; o1.w = f.y; o2.w = f.z; o3.w = f.w; }
        float* op = ob + (size_t)(cq * 4) * NCELL;
        __builtin_nontemporal_store(o0, (f32x4*)op);
        __builtin_nontemporal_store(o1, (f32x4*)(op + (size_t)NCELL));
        __builtin_nontemporal_store(o2, (f32x4*)(op + 2 * (size_t)NCELL));
        __builtin_nontemporal_store(o3, (f32x4*)(op + 3 * (size_t)NCELL));
    }
}

// ---- fallback path (ws too small): zero output + direct scatter ----
__global__ void ppsc_zero(float* __restrict__ out, int n4) {
    int t = blockIdx.x * blockDim.x + threadIdx.x;
    if (t < n4) ((float4*)out)[t] = make_float4(0.f, 0.f, 0.f, 0.f);
}

__global__ void ppsc_direct_scatter(const float* __restrict__ pf,
                                    const int* __restrict__ coords,
                                    float* __restrict__ out) {
    int t = blockIdx.x * blockDim.x + threadIdx.x;  // one thread per (b,p,c)
    if (t >= BB * PP * CC) return;
    int c  = t % CC;
    int bp = t / CC;
    int b  = bp / PP;
    const int* cd = coords + (size_t)bp * 4;
    int y = cd[2], x = cd[3];
    if ((unsigned)y < (unsigned)NYY && (unsigned)x < (unsigned)NXX)
        out[((size_t)(b * CC + c)) * NCELL + (size_t)y * NXX + x] = pf[(size_t)bp * CC + c];
}

extern "C" void kernel_launch(void* const* d_in, const int* in_sizes, int n_in,
                              void* d_out, int out_size, void* d_ws, size_t ws_size,
                              hipStream_t stream) {
    const float* pf     = (const float*)d_in[0];
    const int*   coords = (const int*)d_in[1];
    float*       out    = (float*)d_out;

    const size_t map_bytes = (size_t)BB * NCELL * sizeof(u16);  // 3.43 MB

    if (ws_size >= map_bytes) {
        u16* map16 = (u16*)d_ws;

        int npil = BB * PP;                  // 160000
        ppsc_scatter_map<<<(npil + 255) / 256, 256, 0, stream>>>(coords, map16);

        ppsc_gather_all<<<GNWG, GBLK, 0, stream>>>(pf, map16, coords, out);
    } else {
        int n4_out = out_size / 4;
        ppsc_zero<<<(n4_out + 255) / 256, 256, 0, stream>>>(out, n4_out);

        int nsc = BB * PP * CC;              // 10,240,000
        ppsc_direct_scatter<<<(nsc + 255) / 256, 256, 0, stream>>>(pf, coords, out);
    }
}